// Round 1
// baseline (128.382 us; speedup 1.0000x reference)
//
#include <hip/hip_runtime.h>
#include <stdint.h>

// Croston's method: B=8192 series x T=2048 steps. out = Z'/V' per step.
//
// Round 12: cut warmup read-amplification. R11 analysis: kernel is BW-bound
// at ~75-85% of achievable HBM BW, but CH=128/WARM=128 re-reads 1.94x the
// input (128 + 15*256 = 3968 steps/series vs 2048). CH=256 (NCH=8) amortizes
// the same 128-step warmup over 2x the emitted steps: 256 + 7*384 = 2944
// steps/series = 1.44x  ->  total traffic 188 MB -> 156 MB (-17%).
// Occupancy drops 8 -> 4 waves/CU (1024 waves, 512 blocks, all resident in
// one round); Little's law: 4 waves x 2 tiles x 8KB = 64KB in flight/CU
// >> ~9KB needed at 25 GB/s/CU, so still BW-bound, not latency-bound.
// vmcnt immediates re-audited for 8-tile (c==0) / 12-tile (c>0) sequences
// with the invariant NWAIT(T) = 8*emit(T-1) + 8*refill(T-1); T=0 waits 8
// (prologue's second prime is the only newer op).
// Kept from R11: per-tile-correct vmcnt immediates (extra compiler vmem ops
// only make waits stricter -> safe), XCD swizzle (sg pinned to blockIdx%8),
// global_load_lds 16B DMA staging (no VGPR results -> no compiler waits),
// LDS slot reuse for output transpose (rotation swizzle, R10-verified),
// NT float4 stores, WARM=128 lookback (contraction 0.9^~85 ~1e-4 << bf16
// floor 0.0078; c=0 exact from Z0/V0/q0).

#define TLEN 2048
#define CH   256
#define WARM 128
#define NCH  (TLEN / CH)       // 8
#define TW   32                // slot = 64 rows x 32 steps = 8KB

typedef float vf4 __attribute__((ext_vector_type(4)));

#define GLDS16(gp, lp)                                                        \
    __builtin_amdgcn_global_load_lds(                                         \
        (const __attribute__((address_space(1))) uint32_t*)(gp),              \
        (__attribute__((address_space(3))) uint32_t*)(lp), 16, 0, 0)

// One pipeline stage. NWAIT: vmcnt immediate (tile's own 8 DMA must drain;
// NWAIT = #vmem ops issued after this tile's DMA: 8*refill + 8*prev-stores).
// EMIT/REFILL are compile-time 0/1.
#define TILE(T, NWAIT, EMIT, REFILL) do {                                     \
    float* slot = ((T) & 1) ? ring1 : ring0;                                  \
    const int t0 = t_start + (T) * TW;                                        \
    asm volatile("s_waitcnt vmcnt(" #NWAIT ")" ::: "memory");                 \
    vf4 v[8];                                                                 \
    _Pragma("unroll")                                                         \
    for (int mm = 0; mm < 8; ++mm)                                            \
        v[mm] = *(const vf4*)(slot + lane * 32 + (((mm - k8) & 7) << 2));     \
    asm volatile("s_waitcnt lgkmcnt(0)" ::: "memory");                        \
    if (EMIT) {                                                               \
        _Pragma("unroll")                                                     \
        for (int mm = 0; mm < 8; ++mm) {                                      \
            _Pragma("unroll")                                                 \
            for (int k = 0; k < 4; ++k) {                                     \
                step(v[mm][k]);                                               \
                v[mm][k] = Z * __builtin_amdgcn_rcpf(V);                      \
            }                                                                 \
        }                                                                     \
        _Pragma("unroll")                                                     \
        for (int mm = 0; mm < 8; ++mm)   /* outputs into freed slot */        \
            *(vf4*)(slot + lane * 32 + (((mm - k8) & 7) << 2)) = v[mm];       \
        asm volatile("s_waitcnt lgkmcnt(0)" ::: "memory");                    \
        _Pragma("unroll")                                                     \
        for (int i = 0; i < 8; ++i) {    /* coalesced NT stores */            \
            const float* p = slot + (i * 8 + rho) * 32 + (((k8 - rho) & 7) << 2); \
            vf4 o4; o4.x = p[0]; o4.y = p[1]; o4.z = p[2]; o4.w = p[3];       \
            __builtin_nontemporal_store(                                      \
                o4, (vf4*)(out + (size_t)(sbase + i * 8 + rho) * TLEN + t0 + (k8 << 2))); \
        }                                                                     \
        asm volatile("s_waitcnt lgkmcnt(0)" ::: "memory");                    \
    } else {                                                                  \
        _Pragma("unroll")                                                     \
        for (int mm = 0; mm < 8; ++mm) {                                      \
            _Pragma("unroll")                                                 \
            for (int k = 0; k < 4; ++k) step(v[mm][k]);                       \
        }                                                                     \
    }                                                                         \
    if (REFILL) dma_tile(slot, t0 + 2 * TW);  /* WAR-safe: reads drained */   \
} while (0)

__global__ __launch_bounds__(128) void croston_kernel(
    const float* __restrict__ x,
    const float* __restrict__ alpha,
    const float* __restrict__ Z0,
    const float* __restrict__ V0,
    const float* __restrict__ q0,
    float* __restrict__ out)
{
    __shared__ float ring[2][2][64 * TW];     // [warp][slot][8KB] = 32KB

    const int warp = threadIdx.x >> 6;
    const int lane = threadIdx.x & 63;

    // XCD-locality swizzle (xcd = blockIdx % 8 heuristic; perf-only)
    const int xr = blockIdx.x & 7;
    const int bm = blockIdx.x >> 3;           // 0..63
    const int sg = xr * 16 + (bm & 15);       // series group pinned to XCD xr
    const int c  = (bm >> 4) * 2 + warp;      // chunk 0..7

    const int sbase = sg * 64;
    const int s     = c * CH;
    const int t_start = (c == 0) ? 0 : (s - WARM);

    const float a  = alpha[0];
    const float ma = 1.0f - a;

    float Z, V, q;
    if (c == 0) {                // exact initial state (loads BEFORE DMA prime)
        Z = Z0[sbase + lane];
        V = V0[sbase + lane];
        q = q0[sbase + lane];
    } else {
        Z = 1.0f; V = 1.0f; q = 1.0f;
    }

    const int rho = lane >> 3;               // row-in-octet (0..7)
    const int k8  = lane & 7;                // 16B chunk slot / rotation key
    const int mrot = ((k8 + rho) & 7) * 4;   // DMA-side rotated time offset

    float* ring0 = ring[warp][0];
    float* ring1 = ring[warp][1];

    auto dma_tile = [&](float* slot, int t0) {
        const float* gbase = x + (size_t)(sbase + rho) * TLEN + t0 + mrot;
        #pragma unroll
        for (int i = 0; i < 8; ++i)
            GLDS16(gbase + (size_t)i * 8 * TLEN, slot + i * 256);
    };

    auto step = [&](float xt) {
        const bool  nz = (xt != 0.0f);
        const float Zn = fmaf(ma, Z, a * xt);
        const float Vn = fmaf(ma, V, a * q);
        Z = nz ? Zn : Z;
        V = nz ? Vn : V;
        q = nz ? 1.0f : q + 1.0f;
    };

    dma_tile(ring0, t_start);
    dma_tile(ring1, t_start + TW);           // 16 DMA outstanding

    if (c == 0) {
        // 8 tiles, all emit; refill for T=0..5 (tile T fetches T+2).
        // NWAIT(T) = 8*emit(T-1) + 8*refill(T-1); T0: prologue prime (8).
        TILE(0,  8, 1, 1);
        TILE(1, 16, 1, 1);
        TILE(2, 16, 1, 1);
        TILE(3, 16, 1, 1);
        TILE(4, 16, 1, 1);
        TILE(5, 16, 1, 1);
        TILE(6, 16, 1, 0);   // e5+r5 = 16
        TILE(7,  8, 1, 0);   // e6+r6 = 8
    } else {
        // 12 tiles: 0..3 warmup (no stores), 4..11 emit; refill T=0..9.
        // NWAIT audit per invariant:
        TILE(0,  8, 0, 1);   // prologue prime
        TILE(1,  8, 0, 1);   // e0(0)+r0(8)
        TILE(2,  8, 0, 1);
        TILE(3,  8, 0, 1);
        TILE(4,  8, 1, 1);   // e3(0)+r3(8)
        TILE(5, 16, 1, 1);   // e4(8)+r4(8)
        TILE(6, 16, 1, 1);
        TILE(7, 16, 1, 1);
        TILE(8, 16, 1, 1);
        TILE(9, 16, 1, 1);
        TILE(10, 16, 1, 0);  // e9+r9 = 16
        TILE(11,  8, 1, 0);  // e10+r10 = 8
    }
}

extern "C" void kernel_launch(void* const* d_in, const int* in_sizes, int n_in,
                              void* d_out, int out_size, void* d_ws, size_t ws_size,
                              hipStream_t stream) {
    const float* x     = (const float*)d_in[0];
    const float* alpha = (const float*)d_in[1];
    const float* Z0    = (const float*)d_in[2];
    const float* V0    = (const float*)d_in[3];
    const float* q0    = (const float*)d_in[4];
    float* out = (float*)d_out;

    // 1024 waves = 128 sgs x 8 chunks, 2 independent waves/block,
    // block->XCD swizzled; 4 waves/CU, fully resident in one round.
    dim3 block(128);
    dim3 grid(512);
    croston_kernel<<<grid, block, 0, stream>>>(x, alpha, Z0, V0, q0, out);
}

// Round 2
// 128.136 us; speedup vs baseline: 1.0019x; 1.0019x over previous
//
#include <hip/hip_runtime.h>
#include <stdint.h>

// Croston's method: B=8192 series x T=2048 steps. out = Z'/V' per step.
//
// Round 13: attack latency-boundness. R12 counters: croston at 2.77 TB/s
// (34.7% peak), VALUBusy 12.7%, occupancy 8.3%, conflicts negligible ->
// latency-bound. Root cause: depth-2 ring keeps only ONE 8KB refill in
// flight per wave during compute (vmcnt audit: wait at tile T drains all
// but tile T+1's DMA). Aggregate in-flight reads ~8MB -> ~3 TB/s at ~1us
// loaded latency. Fix: 4-slot ring (32KB/warp, 64KB/block = static LDS
// limit, still 2 blocks/CU -> all 1024 waves resident). Prime 4 tiles,
// refill 4 ahead -> ~24KB reads in flight/wave (~24MB aggregate).
// vmcnt immediates re-audited: NWAIT(T) = #vmem ops issued after tile T's
// DMA (8 per DMA tile, 8 per emit store burst); values 24/32/40/48 < 63.
// Extra compiler vmem ops and c==0 state loads only make waits stricter.
// Kept from R12: CH=256/WARM=128 (1.44x read amp; L3 absorbs ~half),
// XCD swizzle, global_load_lds 16B DMA staging, LDS slot reuse for output
// transpose (rotation swizzle), NT float4 stores, exact c=0 state.

#define TLEN 2048
#define CH   256
#define WARM 128
#define NCH  (TLEN / CH)       // 8
#define TW   32                // slot = 64 rows x 32 steps = 8KB

typedef float vf4 __attribute__((ext_vector_type(4)));

#define GLDS16(gp, lp)                                                        \
    __builtin_amdgcn_global_load_lds(                                         \
        (const __attribute__((address_space(1))) uint32_t*)(gp),              \
        (__attribute__((address_space(3))) uint32_t*)(lp), 16, 0, 0)

// One pipeline stage. NWAIT: vmcnt immediate (tile's own 8 DMA must drain;
// NWAIT = #vmem ops issued after this tile's DMA: refills + store bursts).
// EMIT/REFILL are compile-time 0/1.
#define TILE(T, NWAIT, EMIT, REFILL) do {                                     \
    float* slot = ringS[(T) & 3];                                             \
    const int t0 = t_start + (T) * TW;                                        \
    asm volatile("s_waitcnt vmcnt(" #NWAIT ")" ::: "memory");                 \
    vf4 v[8];                                                                 \
    _Pragma("unroll")                                                         \
    for (int mm = 0; mm < 8; ++mm)                                            \
        v[mm] = *(const vf4*)(slot + lane * 32 + (((mm - k8) & 7) << 2));     \
    asm volatile("s_waitcnt lgkmcnt(0)" ::: "memory");                        \
    if (EMIT) {                                                               \
        _Pragma("unroll")                                                     \
        for (int mm = 0; mm < 8; ++mm) {                                      \
            _Pragma("unroll")                                                 \
            for (int k = 0; k < 4; ++k) {                                     \
                step(v[mm][k]);                                               \
                v[mm][k] = Z * __builtin_amdgcn_rcpf(V);                      \
            }                                                                 \
        }                                                                     \
        _Pragma("unroll")                                                     \
        for (int mm = 0; mm < 8; ++mm)   /* outputs into freed slot */        \
            *(vf4*)(slot + lane * 32 + (((mm - k8) & 7) << 2)) = v[mm];       \
        asm volatile("s_waitcnt lgkmcnt(0)" ::: "memory");                    \
        _Pragma("unroll")                                                     \
        for (int i = 0; i < 8; ++i) {    /* coalesced NT stores */            \
            const float* p = slot + (i * 8 + rho) * 32 + (((k8 - rho) & 7) << 2); \
            vf4 o4; o4.x = p[0]; o4.y = p[1]; o4.z = p[2]; o4.w = p[3];       \
            __builtin_nontemporal_store(                                      \
                o4, (vf4*)(out + (size_t)(sbase + i * 8 + rho) * TLEN + t0 + (k8 << 2))); \
        }                                                                     \
        asm volatile("s_waitcnt lgkmcnt(0)" ::: "memory");                    \
    } else {                                                                  \
        _Pragma("unroll")                                                     \
        for (int mm = 0; mm < 8; ++mm) {                                      \
            _Pragma("unroll")                                                 \
            for (int k = 0; k < 4; ++k) step(v[mm][k]);                       \
        }                                                                     \
    }                                                                         \
    if (REFILL) dma_tile(slot, t0 + 4 * TW);  /* WAR-safe: reads drained */   \
} while (0)

__global__ __launch_bounds__(128) void croston_kernel(
    const float* __restrict__ x,
    const float* __restrict__ alpha,
    const float* __restrict__ Z0,
    const float* __restrict__ V0,
    const float* __restrict__ q0,
    float* __restrict__ out)
{
    __shared__ float ring[2][4][64 * TW];     // [warp][slot][8KB] = 64KB

    const int warp = threadIdx.x >> 6;
    const int lane = threadIdx.x & 63;

    // XCD-locality swizzle (xcd = blockIdx % 8 heuristic; perf-only)
    const int xr = blockIdx.x & 7;
    const int bm = blockIdx.x >> 3;           // 0..63
    const int sg = xr * 16 + (bm & 15);       // series group pinned to XCD xr
    const int c  = (bm >> 4) * 2 + warp;      // chunk 0..7

    const int sbase = sg * 64;
    const int s     = c * CH;
    const int t_start = (c == 0) ? 0 : (s - WARM);

    const float a  = alpha[0];
    const float ma = 1.0f - a;

    float Z, V, q;
    if (c == 0) {                // exact initial state (loads BEFORE DMA prime)
        Z = Z0[sbase + lane];
        V = V0[sbase + lane];
        q = q0[sbase + lane];
    } else {
        Z = 1.0f; V = 1.0f; q = 1.0f;
    }

    const int rho = lane >> 3;               // row-in-octet (0..7)
    const int k8  = lane & 7;                // 16B chunk slot / rotation key
    const int mrot = ((k8 + rho) & 7) * 4;   // DMA-side rotated time offset

    float* ringS[4] = { ring[warp][0], ring[warp][1],
                        ring[warp][2], ring[warp][3] };

    auto dma_tile = [&](float* slot, int t0) {
        const float* gbase = x + (size_t)(sbase + rho) * TLEN + t0 + mrot;
        #pragma unroll
        for (int i = 0; i < 8; ++i)
            GLDS16(gbase + (size_t)i * 8 * TLEN, slot + i * 256);
    };

    auto step = [&](float xt) {
        const bool  nz = (xt != 0.0f);
        const float Zn = fmaf(ma, Z, a * xt);
        const float Vn = fmaf(ma, V, a * q);
        Z = nz ? Zn : Z;
        V = nz ? Vn : V;
        q = nz ? 1.0f : q + 1.0f;
    };

    dma_tile(ringS[0], t_start);              // prime 4 tiles deep
    dma_tile(ringS[1], t_start + TW);
    dma_tile(ringS[2], t_start + 2 * TW);
    dma_tile(ringS[3], t_start + 3 * TW);     // 32 DMA outstanding

    if (c == 0) {
        // 8 tiles, all emit; refill T=0..3 (tile T fetches T+4).
        // Issue order: D0..D3 | T0:[S0,D4] T1:[S1,D5] T2:[S2,D6] T3:[S3,D7]
        //              T4:[S4] T5:[S5] T6:[S6] T7:[S7]
        // NWAIT(T) = vmem ops issued after D_T:
        TILE(0, 24, 1, 1);   // D1,D2,D3
        TILE(1, 32, 1, 1);   // D2,D3,S0,D4
        TILE(2, 40, 1, 1);   // D3,S0,D4,S1,D5
        TILE(3, 48, 1, 1);   // S0,D4,S1,D5,S2,D6
        TILE(4, 48, 1, 0);   // S1,D5,S2,D6,S3,D7
        TILE(5, 40, 1, 0);   // S2,D6,S3,D7,S4
        TILE(6, 32, 1, 0);   // S3,D7,S4,S5
        TILE(7, 24, 1, 0);   // S4,S5,S6
    } else {
        // 12 tiles: 0..3 warmup (no stores), 4..11 emit; refill T=0..7.
        // Issue order: D0..D3 | T0:[D4] T1:[D5] T2:[D6] T3:[D7]
        //   T4:[S4,D8] T5:[S5,D9] T6:[S6,D10] T7:[S7,D11]
        //   T8:[S8] T9:[S9] T10:[S10] T11:[S11]
        TILE(0,  24, 0, 1);  // D1,D2,D3
        TILE(1,  24, 0, 1);  // D2,D3,D4
        TILE(2,  24, 0, 1);  // D3,D4,D5
        TILE(3,  24, 0, 1);  // D4,D5,D6
        TILE(4,  24, 1, 1);  // D5,D6,D7
        TILE(5,  32, 1, 1);  // D6,D7,S4,D8
        TILE(6,  40, 1, 1);  // D7,S4,D8,S5,D9
        TILE(7,  48, 1, 1);  // S4,D8,S5,D9,S6,D10
        TILE(8,  48, 1, 0);  // S5,D9,S6,D10,S7,D11
        TILE(9,  40, 1, 0);  // S6,D10,S7,D11,S8
        TILE(10, 32, 1, 0);  // S7,D11,S8,S9
        TILE(11, 24, 1, 0);  // S8,S9,S10
    }
}

extern "C" void kernel_launch(void* const* d_in, const int* in_sizes, int n_in,
                              void* d_out, int out_size, void* d_ws, size_t ws_size,
                              hipStream_t stream) {
    const float* x     = (const float*)d_in[0];
    const float* alpha = (const float*)d_in[1];
    const float* Z0    = (const float*)d_in[2];
    const float* V0    = (const float*)d_in[3];
    const float* q0    = (const float*)d_in[4];
    float* out = (float*)d_out;

    // 1024 waves = 128 sgs x 8 chunks, 2 independent waves/block,
    // block->XCD swizzled; 4 waves/CU, fully resident in one round.
    dim3 block(128);
    dim3 grid(512);
    croston_kernel<<<grid, block, 0, stream>>>(x, alpha, Z0, V0, q0, out);
}

// Round 3
// 127.978 us; speedup vs baseline: 1.0032x; 1.0012x over previous
//
#include <hip/hip_runtime.h>
#include <stdint.h>

// Croston's method: B=8192 series x T=2048 steps. out = Z'/V' per step.
//
// Round 14: hide LDS ring accesses from the compiler. Evidence R10-R13:
// every pipeline-depth change was a perf no-op (41.8/42.4us, 2.7 TB/s,
// per-wave BW ~2.7 GB/s == ~1 DMA in flight), and BW scaled only with
// wave count (R11 8 waves/CU -> 4.7 TB/s). Diagnosis: LLVM's waitcnt pass
// conservatively drains outstanding global_load_lds (LDS-DMA) before any
// compiler-visible ds_read that may alias -> it inserted vmcnt(0)-class
// waits before EVERY tile's vf4 LDS reads, collapsing the hand pipeline
// to depth-0 regardless of our immediates (in-order vmcnt retire also
// couples NT-store retire into each drain). Fix: ALL ring reads/writes
// are inline-asm ds_read_b128/ds_write_b128 with s_waitcnt lgkmcnt(0)
// inside the same asm block (no hoisting hazard by construction); ring is
// touched only by asm + the DMA builtin, so the only vmcnt waits left are
// our audited immediates. Compiler-only memory fence between store burst
// and refill pins the issue order the NWAIT audit assumes.
// Kept from R13: 4-slot ring (32KB/warp, 64KB/block, 2 blocks/CU, all
// 1024 waves resident), CH=256/WARM=128, XCD swizzle, 16B DMA staging,
// slot-reuse output transpose (rotation swizzle), NT float4 stores,
// exact c=0 state, NWAIT table (issue order unchanged).

#define TLEN 2048
#define CH   256
#define WARM 128
#define NCH  (TLEN / CH)       // 8
#define TW   32                // slot = 64 rows x 32 steps = 8KB

typedef float vf4 __attribute__((ext_vector_type(4)));

#define GLDS16(gp, lp)                                                        \
    __builtin_amdgcn_global_load_lds(                                         \
        (const __attribute__((address_space(1))) uint32_t*)(gp),              \
        (__attribute__((address_space(3))) uint32_t*)(lp), 16, 0, 0)

#define LDSOFF(p) ((uint32_t)(uintptr_t)(__attribute__((address_space(3))) float*)(p))

// 8x ds_read_b128 + drain, one asm block: compiler sees no LDS read, so it
// cannot insert LDS-DMA vmcnt drains; lgkmcnt(0) inside => outputs valid.
#define DS_READ8(vv, aa)                                                      \
    asm volatile(                                                             \
        "ds_read_b128 %0, %8\n\t"                                             \
        "ds_read_b128 %1, %9\n\t"                                             \
        "ds_read_b128 %2, %10\n\t"                                            \
        "ds_read_b128 %3, %11\n\t"                                            \
        "ds_read_b128 %4, %12\n\t"                                            \
        "ds_read_b128 %5, %13\n\t"                                            \
        "ds_read_b128 %6, %14\n\t"                                            \
        "ds_read_b128 %7, %15\n\t"                                            \
        "s_waitcnt lgkmcnt(0)"                                                \
        : "=&v"(vv[0]), "=&v"(vv[1]), "=&v"(vv[2]), "=&v"(vv[3]),             \
          "=&v"(vv[4]), "=&v"(vv[5]), "=&v"(vv[6]), "=&v"(vv[7])              \
        : "v"(aa[0]), "v"(aa[1]), "v"(aa[2]), "v"(aa[3]),                     \
          "v"(aa[4]), "v"(aa[5]), "v"(aa[6]), "v"(aa[7])                      \
        : "memory")

#define DS_WRITE8(vv, aa)                                                     \
    asm volatile(                                                             \
        "ds_write_b128 %8, %0\n\t"                                            \
        "ds_write_b128 %9, %1\n\t"                                            \
        "ds_write_b128 %10, %2\n\t"                                           \
        "ds_write_b128 %11, %3\n\t"                                           \
        "ds_write_b128 %12, %4\n\t"                                           \
        "ds_write_b128 %13, %5\n\t"                                           \
        "ds_write_b128 %14, %6\n\t"                                           \
        "ds_write_b128 %15, %7\n\t"                                           \
        "s_waitcnt lgkmcnt(0)"                                                \
        :                                                                     \
        : "v"(vv[0]), "v"(vv[1]), "v"(vv[2]), "v"(vv[3]),                     \
          "v"(vv[4]), "v"(vv[5]), "v"(vv[6]), "v"(vv[7]),                     \
          "v"(aa[0]), "v"(aa[1]), "v"(aa[2]), "v"(aa[3]),                     \
          "v"(aa[4]), "v"(aa[5]), "v"(aa[6]), "v"(aa[7])                      \
        : "memory")

// One pipeline stage. NWAIT: vmcnt immediate (tile's own 8 DMA must drain;
// NWAIT = #vmem ops issued after this tile's DMA: refills + store bursts).
// EMIT/REFILL are compile-time 0/1.
#define TILE(T, NWAIT, EMIT, REFILL) do {                                     \
    float* slot = ringS[(T) & 3];                                             \
    const int t0 = t_start + (T) * TW;                                        \
    uint32_t ain[8];                                                          \
    _Pragma("unroll")                                                         \
    for (int mm = 0; mm < 8; ++mm)                                            \
        ain[mm] = LDSOFF(slot + lane * 32 + (((mm - k8) & 7) << 2));          \
    asm volatile("s_waitcnt vmcnt(" #NWAIT ")" ::: "memory");                 \
    vf4 v[8];                                                                 \
    DS_READ8(v, ain);                                                         \
    if (EMIT) {                                                               \
        _Pragma("unroll")                                                     \
        for (int mm = 0; mm < 8; ++mm) {                                      \
            _Pragma("unroll")                                                 \
            for (int k = 0; k < 4; ++k) {                                     \
                step(v[mm][k]);                                               \
                v[mm][k] = Z * __builtin_amdgcn_rcpf(V);                      \
            }                                                                 \
        }                                                                     \
        DS_WRITE8(v, ain);               /* outputs into freed slot */        \
        uint32_t bst[8];                                                      \
        _Pragma("unroll")                                                     \
        for (int i = 0; i < 8; ++i)                                           \
            bst[i] = LDSOFF(slot + (i * 8 + rho) * 32 + (((k8 - rho) & 7) << 2)); \
        vf4 o[8];                                                             \
        DS_READ8(o, bst);                /* transposed; slot free after */    \
        _Pragma("unroll")                                                     \
        for (int i = 0; i < 8; ++i)      /* coalesced NT stores */            \
            __builtin_nontemporal_store(                                      \
                o[i], (vf4*)(out + (size_t)(sbase + i * 8 + rho) * TLEN + t0 + (k8 << 2))); \
        asm volatile("" ::: "memory");   /* pin store-before-refill order */  \
    } else {                                                                  \
        _Pragma("unroll")                                                     \
        for (int mm = 0; mm < 8; ++mm) {                                      \
            _Pragma("unroll")                                                 \
            for (int k = 0; k < 4; ++k) step(v[mm][k]);                       \
        }                                                                     \
    }                                                                         \
    if (REFILL) dma_tile(slot, t0 + 4 * TW);  /* WAR-safe: reads drained */   \
} while (0)

__global__ __launch_bounds__(128) void croston_kernel(
    const float* __restrict__ x,
    const float* __restrict__ alpha,
    const float* __restrict__ Z0,
    const float* __restrict__ V0,
    const float* __restrict__ q0,
    float* __restrict__ out)
{
    __shared__ __attribute__((aligned(16))) float ring[2][4][64 * TW]; // 64KB

    const int warp = threadIdx.x >> 6;
    const int lane = threadIdx.x & 63;

    // XCD-locality swizzle (xcd = blockIdx % 8 heuristic; perf-only)
    const int xr = blockIdx.x & 7;
    const int bm = blockIdx.x >> 3;           // 0..63
    const int sg = xr * 16 + (bm & 15);       // series group pinned to XCD xr
    const int c  = (bm >> 4) * 2 + warp;      // chunk 0..7

    const int sbase = sg * 64;
    const int s     = c * CH;
    const int t_start = (c == 0) ? 0 : (s - WARM);

    const float a  = alpha[0];
    const float ma = 1.0f - a;

    float Z, V, q;
    if (c == 0) {                // exact initial state (loads BEFORE DMA prime)
        Z = Z0[sbase + lane];
        V = V0[sbase + lane];
        q = q0[sbase + lane];
    } else {
        Z = 1.0f; V = 1.0f; q = 1.0f;
    }

    const int rho = lane >> 3;               // row-in-octet (0..7)
    const int k8  = lane & 7;                // 16B chunk slot / rotation key
    const int mrot = ((k8 + rho) & 7) * 4;   // DMA-side rotated time offset

    float* ringS[4] = { ring[warp][0], ring[warp][1],
                        ring[warp][2], ring[warp][3] };

    auto dma_tile = [&](float* slot, int t0) {
        const float* gbase = x + (size_t)(sbase + rho) * TLEN + t0 + mrot;
        #pragma unroll
        for (int i = 0; i < 8; ++i)
            GLDS16(gbase + (size_t)i * 8 * TLEN, slot + i * 256);
    };

    auto step = [&](float xt) {
        const bool  nz = (xt != 0.0f);
        const float Zn = fmaf(ma, Z, a * xt);
        const float Vn = fmaf(ma, V, a * q);
        Z = nz ? Zn : Z;
        V = nz ? Vn : V;
        q = nz ? 1.0f : q + 1.0f;
    };

    dma_tile(ringS[0], t_start);              // prime 4 tiles deep
    dma_tile(ringS[1], t_start + TW);
    dma_tile(ringS[2], t_start + 2 * TW);
    dma_tile(ringS[3], t_start + 3 * TW);     // 32 DMA outstanding

    if (c == 0) {
        // 8 tiles, all emit; refill T=0..3 (tile T fetches T+4).
        // Issue order: D0..D3 | T0:[S0,D4] T1:[S1,D5] T2:[S2,D6] T3:[S3,D7]
        //              T4:[S4] T5:[S5] T6:[S6] T7:[S7]
        // NWAIT(T) = vmem ops issued after D_T:
        TILE(0, 24, 1, 1);   // D1,D2,D3
        TILE(1, 32, 1, 1);   // D2,D3,S0,D4
        TILE(2, 40, 1, 1);   // D3,S0,D4,S1,D5
        TILE(3, 48, 1, 1);   // S0,D4,S1,D5,S2,D6
        TILE(4, 48, 1, 0);   // S1,D5,S2,D6,S3,D7
        TILE(5, 40, 1, 0);   // S2,D6,S3,D7,S4
        TILE(6, 32, 1, 0);   // S3,D7,S4,S5
        TILE(7, 24, 1, 0);   // S4,S5,S6
    } else {
        // 12 tiles: 0..3 warmup (no stores), 4..11 emit; refill T=0..7.
        // Issue order: D0..D3 | T0:[D4] T1:[D5] T2:[D6] T3:[D7]
        //   T4:[S4,D8] T5:[S5,D9] T6:[S6,D10] T7:[S7,D11]
        //   T8:[S8] T9:[S9] T10:[S10] T11:[S11]
        TILE(0,  24, 0, 1);  // D1,D2,D3
        TILE(1,  24, 0, 1);  // D2,D3,D4
        TILE(2,  24, 0, 1);  // D3,D4,D5
        TILE(3,  24, 0, 1);  // D4,D5,D6
        TILE(4,  24, 1, 1);  // D5,D6,D7
        TILE(5,  32, 1, 1);  // D6,D7,S4,D8
        TILE(6,  40, 1, 1);  // D7,S4,D8,S5,D9
        TILE(7,  48, 1, 1);  // S4,D8,S5,D9,S6,D10
        TILE(8,  48, 1, 0);  // S5,D9,S6,D10,S7,D11
        TILE(9,  40, 1, 0);  // S6,D10,S7,D11,S8
        TILE(10, 32, 1, 0);  // S7,D11,S8,S9
        TILE(11, 24, 1, 0);  // S8,S9,S10
    }
}

extern "C" void kernel_launch(void* const* d_in, const int* in_sizes, int n_in,
                              void* d_out, int out_size, void* d_ws, size_t ws_size,
                              hipStream_t stream) {
    const float* x     = (const float*)d_in[0];
    const float* alpha = (const float*)d_in[1];
    const float* Z0    = (const float*)d_in[2];
    const float* V0    = (const float*)d_in[3];
    const float* q0    = (const float*)d_in[4];
    float* out = (float*)d_out;

    // 1024 waves = 128 sgs x 8 chunks, 2 independent waves/block,
    // block->XCD swizzled; 4 waves/CU, fully resident in one round.
    dim3 block(128);
    dim3 grid(512);
    croston_kernel<<<grid, block, 0, stream>>>(x, alpha, Z0, V0, q0, out);
}

// Round 5
// 126.316 us; speedup vs baseline: 1.0164x; 1.0132x over previous
//
#include <hip/hip_runtime.h>
#include <stdint.h>

// Croston's method: B=8192 series x T=2048 steps. out = Z'/V' per step.
//
// Round 16 = Round 15 with the compile fix (step takes float BY VALUE; a
// non-const reference cannot bind to an ext_vector element).
//
// R15 rationale: drop global_load_lds entirely; reg-stage through VGPRs.
// Evidence R10-R14: per-wave read BW pinned at ~2.7 GB/s for EVERY software
// pipeline depth (2/4-slot ring, asm-hidden ds ops, audited vmcnt) and BW
// scales only with wave count -> the LDS-DMA path itself has a small
// per-wave HW concurrency limit (~2-3 outstanding 1KB requests). Software
// vmcnt audits were managing a queue the HW never deepens.
// Fix: ordinary global_load_dwordx4 -> VGPR staging (depth-3 tiles =
// 24KB/wave in flight, limited only by vmcnt=63 + VGPRs), then vf4 stores
// into the SAME verified LDS rotation layout, plain compiler-scheduled
// code (no inline asm anywhere; VGPR dataflow is the path the compiler
// schedules with counted vmcnt). CH=128 again: 2048 waves, 8 waves/CU
// (2/SIMD) for TLP to hide the wave-side LDS roundtrip; R12 FETCH counter
// (47.6MB < 64MB input) shows x is L3-resident, so warmup re-reads are
// nearly HBM-free. LDS 32KB/block -> all 1024 blocks resident (128KB/CU).
// Kept: XCD swizzle, slot-reuse output transpose (R10-verified rotation
// mapping, copied verbatim), NT float4 stores, WARM=128, exact c=0 state.

#define TLEN 2048
#define CH   128
#define WARM 128
#define TW   32                // tile = 64 rows x 32 steps = 8KB

typedef float vf4 __attribute__((ext_vector_type(4)));

__global__ __launch_bounds__(128) void croston_kernel(
    const float* __restrict__ x,
    const float* __restrict__ alpha,
    const float* __restrict__ Z0,
    const float* __restrict__ V0,
    const float* __restrict__ q0,
    float* __restrict__ out)
{
    __shared__ __attribute__((aligned(16))) float ring[2][2][64 * TW]; // 32KB

    const int warp = threadIdx.x >> 6;
    const int lane = threadIdx.x & 63;

    // XCD-locality swizzle (xcd = blockIdx % 8 heuristic; perf-only)
    const int xr = blockIdx.x & 7;
    const int bm = blockIdx.x >> 3;           // 0..127
    const int sg = xr * 16 + (bm & 15);       // series group pinned to XCD xr
    const int c  = (bm >> 4) * 2 + warp;      // chunk 0..15

    const int sbase = sg * 64;
    const int t_start = (c == 0) ? 0 : (c * CH - WARM);

    const float a  = alpha[0];
    const float ma = 1.0f - a;

    float Z, V, q;
    if (c == 0) {
        Z = Z0[sbase + lane];
        V = V0[sbase + lane];
        q = q0[sbase + lane];
    } else {
        Z = 1.0f; V = 1.0f; q = 1.0f;
    }

    const int rho = lane >> 3;               // row-in-octet (0..7)
    const int k8  = lane & 7;                // 16B chunk slot / rotation key
    const int mrot = ((k8 + rho) & 7) * 4;   // staging-side rotated time offset

    float* ring0 = ring[warp][0];
    float* ring1 = ring[warp][1];

    // Coalesced 16B loads, identical addresses to the old DMA.
    auto load_tile = [&](vf4* st, int t0) {
        const float* gbase = x + (size_t)(sbase + rho) * TLEN + t0 + mrot;
        #pragma unroll
        for (int i = 0; i < 8; ++i)
            st[i] = *(const vf4*)(gbase + (size_t)i * 8 * TLEN);
    };

    auto step = [&](float xt) {              // BY VALUE (compile fix)
        const bool  nz = (xt != 0.0f);
        const float Zn = fmaf(ma, Z, a * xt);
        const float Vn = fmaf(ma, V, a * q);
        Z = nz ? Zn : Z;
        V = nz ? Vn : V;
        q = nz ? 1.0f : q + 1.0f;
    };

    // One tile: stage VGPR->LDS (rotation layout the old DMA produced),
    // read rows, run recurrence; on emit, write outputs into the freed
    // slot, read back transposed, NT-store coalesced.
    auto tile = [&](vf4* st, int T, bool emit) {
        float* slot = (T & 1) ? ring1 : ring0;
        const int t0 = t_start + T * TW;
        #pragma unroll
        for (int i = 0; i < 8; ++i)            // lane's 16B at byte l*16 (+1KB/i)
            *(vf4*)(slot + i * 256 + lane * 4) = st[i];
        vf4 v[8];
        #pragma unroll
        for (int mm = 0; mm < 8; ++mm)
            v[mm] = *(const vf4*)(slot + lane * 32 + (((mm - k8) & 7) << 2));
        if (emit) {
            #pragma unroll
            for (int mm = 0; mm < 8; ++mm) {
                #pragma unroll
                for (int k = 0; k < 4; ++k) {
                    step(v[mm][k]);
                    v[mm][k] = Z * __builtin_amdgcn_rcpf(V);
                }
            }
            #pragma unroll
            for (int mm = 0; mm < 8; ++mm)     // outputs into freed slot
                *(vf4*)(slot + lane * 32 + (((mm - k8) & 7) << 2)) = v[mm];
            #pragma unroll
            for (int i = 0; i < 8; ++i) {      // coalesced NT stores
                const float* p = slot + (i * 8 + rho) * 32 + (((k8 - rho) & 7) << 2);
                vf4 o4; o4.x = p[0]; o4.y = p[1]; o4.z = p[2]; o4.w = p[3];
                __builtin_nontemporal_store(
                    o4, (vf4*)(out + (size_t)(sbase + i * 8 + rho) * TLEN + t0 + (k8 << 2)));
            }
        } else {
            #pragma unroll
            for (int mm = 0; mm < 8; ++mm) {
                #pragma unroll
                for (int k = 0; k < 4; ++k) step(v[mm][k]);
            }
        }
    };

    // Depth-3 register staging (named arrays: all indices compile-time).
    vf4 stA[8], stB[8], stC[8];
    load_tile(stA, t_start);
    load_tile(stB, t_start + TW);
    load_tile(stC, t_start + 2 * TW);

    if (c == 0) {
        // 4 emit tiles.
        tile(stA, 0, true);  load_tile(stA, t_start + 3 * TW);
        tile(stB, 1, true);
        tile(stC, 2, true);
        tile(stA, 3, true);
    } else {
        // 8 tiles: 0..3 warmup, 4..7 emit; refill 3 tiles ahead.
        tile(stA, 0, false); load_tile(stA, t_start + 3 * TW);
        tile(stB, 1, false); load_tile(stB, t_start + 4 * TW);
        tile(stC, 2, false); load_tile(stC, t_start + 5 * TW);
        tile(stA, 3, false); load_tile(stA, t_start + 6 * TW);
        tile(stB, 4, true);  load_tile(stB, t_start + 7 * TW);
        tile(stC, 5, true);
        tile(stA, 6, true);
        tile(stB, 7, true);
    }
}

extern "C" void kernel_launch(void* const* d_in, const int* in_sizes, int n_in,
                              void* d_out, int out_size, void* d_ws, size_t ws_size,
                              hipStream_t stream) {
    const float* x     = (const float*)d_in[0];
    const float* alpha = (const float*)d_in[1];
    const float* Z0    = (const float*)d_in[2];
    const float* V0    = (const float*)d_in[3];
    const float* q0    = (const float*)d_in[4];
    float* out = (float*)d_out;

    // 2048 waves = 128 sgs x 16 chunks, 2 independent waves/block,
    // block->XCD swizzled; 8 waves/CU (2/SIMD), all resident in one round.
    dim3 block(128);
    dim3 grid(1024);
    croston_kernel<<<grid, block, 0, stream>>>(x, alpha, Z0, V0, q0, out);
}